// Round 12
// baseline (295.196 us; speedup 1.0000x reference)
//
#include <hip/hip_runtime.h>
#include <hip/hip_fp8.h>
#include <math.h>

#define D 64
#define BN_EPS 1e-5f
#define CH 160          // edges per chunk (edge_agg work unit)
#define BSH 7           // bucket = 128 consecutive dst nodes
#define BCAP 8192       // per-bucket LDS capacity in bucket_csr (mean ~1600)
#define NBLK 256        // fat blocks for matrix binning
#define NREP 16         // stat-accumulator replicas (contention control)

using short8 = __attribute__((ext_vector_type(8))) short;
using f32x4  = __attribute__((ext_vector_type(4))) float;

static __device__ __forceinline__ unsigned short f2bf(float f) {
    unsigned int u = __float_as_uint(f);
    unsigned int r = (u + 0x7fffu + ((u >> 16) & 1u)) >> 16;
    return (unsigned short)r;
}
static __device__ __forceinline__ float bf2f(unsigned short u) {
    return __uint_as_float(((unsigned int)u) << 16);
}
static __device__ __forceinline__ float clamp60(float x) {
    return fminf(fmaxf(x, -60.f), 60.f);
}
static __device__ __forceinline__ float fp8tof(unsigned char b) {
    __hip_fp8_e4m3 t; t.__x = (__hip_fp8_storage_t)b;
    return (float)t;
}

// ---------------- merged: weight prep (blocks 0..127) + bucket histogram (blocks 128..383) ----------------
__global__ __launch_bounds__(256) void prep_bin(
    const float* __restrict__ Wk, const float* __restrict__ Wq,
    const float* __restrict__ Wv, const float* __restrict__ Ws,
    unsigned short* __restrict__ Wfrag,
    const int* __restrict__ dst, int* __restrict__ cnt, int nedges, int NB)
{
    const int t = threadIdx.x;
    if (blockIdx.x < 128) {
        int idx = blockIdx.x * 256 + t;      // 32768 total
        int i    = idx & 7;
        int lane = (idx >> 3) & 63;
        int kb   = (idx >> 9) & 1;
        int nc   = (idx >> 10) & 3;
        int m    = (idx >> 12) & 3;
        int l    = (idx >> 14) & 1;
        int k = kb * 32 + (lane >> 4) * 8 + i;
        int n = nc * 16 + (lane & 15);
        const float* W = (m == 0) ? Wk : (m == 1) ? Wq : (m == 2) ? Wv : Ws;
        Wfrag[idx] = f2bf(W[(size_t)l * 4096 + k * 64 + n]);
    } else {
        __shared__ int h[1024];
        const int b = blockIdx.x - 128;
        for (int i = t; i < NB; i += 256) h[i] = 0;
        __syncthreads();
        const int e0 = (int)(((long long)nedges * b) / NBLK);
        const int e1 = (int)(((long long)nedges * (b + 1)) / NBLK);
        for (int i = e0 + t; i < e1; i += 256)
            atomicAdd(&h[dst[i] >> BSH], 1);
        __syncthreads();
        for (int i = t; i < NB; i += 256) cnt[b * NB + i] = h[i];
    }
}

// ---------------- fused 4-GEMM via MFMA ----------------
// EKh = bf16(exp(-clamp k)); V16 = bf16(v); EQ8 = e4m3(exp(-clamp q)); AGG = x@Ws+bs+bias.
template<bool APPLY_BN>
__global__ __launch_bounds__(256) void gemm_fused(
    const float* x,                       // may alias AGG (own rows only)
    const unsigned short* __restrict__ Wfrag,
    const float* __restrict__ bk, const float* __restrict__ bq,
    const float* __restrict__ bv, const float* __restrict__ bs,
    const float* __restrict__ bias, const float* __restrict__ stats,
    const float* __restrict__ gamma, const float* __restrict__ beta,
    unsigned short* __restrict__ EKh, unsigned short* __restrict__ V16,
    unsigned char* __restrict__ EQ8, float* AGG, int nrows)
{
    __shared__ unsigned short xt[64 * 64];   // bf16 tile, XOR-swizzled 16B chunks
    __shared__ float scsh[128];              // [sc 0..63 | sh 64..127]
    const int t = threadIdx.x;
    const int row0 = blockIdx.x * 64;

    if (APPLY_BN) {
        if (t < 64) {
            float s = 0.f, q = 0.f;
            #pragma unroll
            for (int rep = 0; rep < NREP; ++rep) {
                s += stats[rep * 128 + t];
                q += stats[rep * 128 + 64 + t];
            }
            float invN = 1.0f / (float)nrows;
            float mean = s * invN;
            float var  = q * invN - mean * mean;
            float sc   = gamma[t] * rsqrtf(var + BN_EPS);
            scsh[t] = sc;
            scsh[64 + t] = beta[t] - mean * sc;
        }
        __syncthreads();
    }

    #pragma unroll
    for (int it = 0; it < 4; ++it) {
        int fidx = t + it * 256;
        int r = fidx >> 4, c4 = fidx & 15;
        int grow = row0 + r;
        float4 v = make_float4(0.f, 0.f, 0.f, 0.f);
        if (grow < nrows)
            v = *reinterpret_cast<const float4*>(&x[(size_t)grow * D + c4 * 4]);
        if (APPLY_BN) {
            float4 sc = reinterpret_cast<const float4*>(scsh)[c4];
            float4 sh = reinterpret_cast<const float4*>(scsh)[16 + c4];
            v.x = fmaxf(v.x, 0.f) * sc.x + sh.x;
            v.y = fmaxf(v.y, 0.f) * sc.y + sh.y;
            v.z = fmaxf(v.z, 0.f) * sc.z + sh.z;
            v.w = fmaxf(v.w, 0.f) * sc.w + sh.w;
        }
        ushort4 b;
        b.x = f2bf(v.x); b.y = f2bf(v.y); b.z = f2bf(v.z); b.w = f2bf(v.w);
        int phys = (c4 >> 1) ^ (r & 7);      // 16B-chunk XOR swizzle
        *reinterpret_cast<ushort4*>(&xt[r * 64 + phys * 8 + (c4 & 1) * 4]) = b;
    }
    __syncthreads();

    const int w = t >> 6, lane = t & 63;
    const int rbase = w * 16;

    short8 A[2];
    #pragma unroll
    for (int kb = 0; kb < 2; ++kb) {
        int r = rbase + (lane & 15);
        int c16 = (kb * 4 + (lane >> 4)) ^ (r & 7);
        A[kb] = *reinterpret_cast<const short8*>(&xt[r * 64 + c16 * 8]);
    }

    f32x4 acc[4][4];
    #pragma unroll
    for (int m = 0; m < 4; ++m)
        #pragma unroll
        for (int nc = 0; nc < 4; ++nc)
            acc[m][nc] = (f32x4){0.f, 0.f, 0.f, 0.f};

    #pragma unroll
    for (int nc = 0; nc < 4; ++nc) {
        #pragma unroll
        for (int m = 0; m < 4; ++m) {
            #pragma unroll
            for (int kb = 0; kb < 2; ++kb) {
                short8 B = *reinterpret_cast<const short8*>(
                    &Wfrag[((((m * 4 + nc) * 2 + kb) * 64) + lane) * 8]);
                acc[m][nc] = __builtin_amdgcn_mfma_f32_16x16x32_bf16(A[kb], B, acc[m][nc], 0, 0, 0);
            }
        }
    }

    const int crow = rbase + ((lane >> 4) << 2);
    #pragma unroll
    for (int nc = 0; nc < 4; ++nc) {
        int c = nc * 16 + (lane & 15);
        float bkc = bk[c], bqc = bq[c], bvc = bv[c], bsc = bs[c] + bias[c];
        #pragma unroll
        for (int reg = 0; reg < 4; ++reg) {
            int grow = row0 + crow + reg;
            if (grow < nrows) {
                size_t o = (size_t)grow * D + c;
                EKh[o] = f2bf(__expf(-clamp60(acc[0][nc][reg] + bkc)));
                float eqf = __expf(-clamp60(acc[1][nc][reg] + bqc));
                EQ8[o] = (unsigned char)__hip_cvt_float_to_fp8(eqf, __HIP_SATFINITE, __HIP_E4M3);
                V16[o] = f2bf(acc[2][nc][reg] + bvc);
                AGG[o] = acc[3][nc][reg] + bsc;
            }
        }
    }
}

// ---------------- matrix-binned CSR build (zero global atomics) ----------------
__global__ __launch_bounds__(256) void scan_mat(const int* __restrict__ cnt,
                                                int* __restrict__ basel,
                                                int* __restrict__ btot, int NB)
{
    __shared__ int tmp[256];
    const int k = blockIdx.x;    // bucket
    const int t = threadIdx.x;   // block index
    int v = cnt[t * NB + k];
    tmp[t] = v;
    __syncthreads();
    for (int off = 1; off < 256; off <<= 1) {
        int add = (t >= off) ? tmp[t - off] : 0;
        __syncthreads();
        tmp[t] += add;
        __syncthreads();
    }
    basel[t * NB + k] = tmp[t] - v;
    if (t == 255) btot[k] = tmp[255];
}

__global__ __launch_bounds__(1024) void scan_buckets(const int* __restrict__ btot,
                                                     int* __restrict__ boff,
                                                     float* __restrict__ stats,
                                                     int* __restrict__ offs,
                                                     int NB, int n, int nedges)
{
    __shared__ int tmp[1024];
    const int t = threadIdx.x;
    int v = (t < NB) ? btot[t] : 0;
    tmp[t] = v;
    __syncthreads();
    for (int off = 1; off < 1024; off <<= 1) {
        int add = (t >= off) ? tmp[t - off] : 0;
        __syncthreads();
        tmp[t] += add;
        __syncthreads();
    }
    if (t < NB) boff[t] = tmp[t] - v;
    for (int i = t; i < 2 * NREP * 128; i += 1024) stats[i] = 0.f;
    if (t == 0) offs[n] = nedges;
}

__global__ __launch_bounds__(256) void bin_emit(const int* __restrict__ src,
                                                const int* __restrict__ dst,
                                                const int* __restrict__ basel,
                                                const int* __restrict__ boff,
                                                unsigned int* __restrict__ bin,
                                                int nedges, int NB)
{
    __shared__ int cur[1024];
    const int t = threadIdx.x, b = blockIdx.x;
    for (int i = t; i < NB; i += 256) cur[i] = boff[i] + basel[b * NB + i];
    __syncthreads();
    const int e0 = (int)(((long long)nedges * b) / NBLK);
    const int e1 = (int)(((long long)nedges * (b + 1)) / NBLK);
    for (int i = e0 + t; i < e1; i += 256) {
        int d = dst[i];
        int pos = atomicAdd(&cur[d >> BSH], 1);
        bin[pos] = ((unsigned int)src[i] << BSH) | (unsigned int)(d & ((1 << BSH) - 1));
    }
}

__global__ __launch_bounds__(256) void bucket_csr(const unsigned int* __restrict__ bin,
                                                  const int* __restrict__ boff,
                                                  const int* __restrict__ btot,
                                                  int* __restrict__ offs,
                                                  int* __restrict__ csr_src, int n)
{
    __shared__ unsigned int lsrc[BCAP];
    __shared__ int ldeg[128], loff[128], lcur[128];
    const int t = threadIdx.x;
    const int b = blockIdx.x;
    const int base = boff[b];
    const int cnt  = btot[b];

    if (t < 128) ldeg[t] = 0;
    __syncthreads();
    for (int j = t; j < cnt; j += 256)
        atomicAdd(&ldeg[bin[base + j] & ((1 << BSH) - 1)], 1);
    __syncthreads();
    if (t < 128) loff[t] = ldeg[t];
    __syncthreads();
    for (int off = 1; off < 128; off <<= 1) {
        int add = (t < 128 && t >= off) ? loff[t - off] : 0;
        __syncthreads();
        if (t < 128) loff[t] += add;
        __syncthreads();
    }
    if (t < 128) {
        int ex = loff[t] - ldeg[t];
        lcur[t] = ex;
        int node = (b << BSH) + t;
        if (node < n) offs[node] = base + ex;
    }
    __syncthreads();
    for (int j = t; j < cnt; j += 256) {
        unsigned int e = bin[base + j];
        int pos = atomicAdd(&lcur[e & ((1 << BSH) - 1)], 1);
        lsrc[pos] = e >> BSH;
    }
    __syncthreads();
    for (int j = t; j < cnt; j += 256)
        csr_src[base + j] = (int)lsrc[j];
}

__global__ __launch_bounds__(256) void nstart_bs(const int* __restrict__ offs,
                                                 int* __restrict__ node_start,
                                                 int n, int NC)
{
    int c = blockIdx.x * 256 + threadIdx.x;
    if (c >= NC) return;
    int target = c * CH;
    int a = 0, bnd = n;
    while (a < bnd) {
        int mid = (a + bnd) >> 1;
        if (offs[mid + 1] > target) bnd = mid; else a = mid + 1;
    }
    node_start[c] = a;
}

// ---------------- edge-parallel aggregation + fused BN stats (replicated accumulators) ----------------
__global__ __launch_bounds__(256) void edge_agg(
    const int* __restrict__ csr_src, const int* __restrict__ offs,
    const int* __restrict__ node_start,
    const unsigned short* __restrict__ EKh, const unsigned short* __restrict__ V16,
    const unsigned char* __restrict__ EQ8,
    float* __restrict__ AGG, float* __restrict__ stats, int nnodes)
{
    const int t = threadIdx.x;
    const int lane  = t & 63;
    const int chunk = __builtin_amdgcn_readfirstlane((int)((blockIdx.x * 256 + t) >> 6));
    const int Etot  = offs[nnodes];
    const int e0 = chunk * CH;
    float lsum = 0.f, lsq = 0.f;

    if (e0 < Etot) {
        const int e1 = min(e0 + CH, Etot);

        int n      = node_start[chunk];
        int nstart = offs[n];
        int nend   = offs[n + 1];

        float acc = 0.f;
        float ek  = bf2f(EKh[((size_t)n << 6) | lane]);

        auto flush = [&](bool partial) {
            int idx = (n << 6) | lane;
            if (partial) {
                atomicAdd(&AGG[idx], acc);
            } else {
                float cur = AGG[idx] + acc;      // final value: all edges owned here
                AGG[idx] = cur;
                float y = fmaxf(cur, 0.f);
                lsum += y;
                lsq = fmaf(y, y, lsq);
            }
        };
        auto advance = [&](int eidx) {
            do { ++n; } while (offs[n + 1] == eidx);   // skip empty nodes
            nstart = eidx;
            nend   = offs[n + 1];
            acc = 0.f;
            ek  = bf2f(EKh[((size_t)n << 6) | lane]);
        };

        for (int e = e0; e < e1; e += 64) {
            const int cnt = min(64, e1 - e);
            int sAll = (lane < cnt) ? csr_src[e + lane] : 0;
            for (int b = 0; b < cnt; b += 16) {
                const int bc = min(16, cnt - b);
                unsigned short pv[16];
                unsigned char pe[16];
                #pragma unroll
                for (int u = 0; u < 16; ++u) {
                    if (u < bc) {
                        int s = __shfl(sAll, b + u);
                        pv[u] = V16[((size_t)s << 6) | lane];
                        pe[u] = EQ8[((size_t)s << 6) | lane];
                    }
                }
                #pragma unroll
                for (int u = 0; u < 16; ++u) {
                    if (u < bc) {
                        int eidx = e + b + u;
                        if (eidx == nend) { flush(nstart < e0); advance(eidx); }
                        float eq = fp8tof(pe[u]);
                        float vv = bf2f(pv[u]);
                        float g  = __builtin_amdgcn_rcpf(fmaf(ek, eq, 1.0f));
                        acc = fmaf(g, vv, acc);
                    }
                }
            }
        }
        flush((nstart < e0) || (nend > e1));
    }

    __shared__ float ss[256], sq2[256];
    ss[t] = lsum; sq2[t] = lsq;
    __syncthreads();
    if (t < 64) {
        float* st = stats + ((blockIdx.x & (NREP - 1)) << 7);
        float s4 = ss[t] + ss[t + 64] + ss[t + 128] + ss[t + 192];
        float q4 = sq2[t] + sq2[t + 64] + sq2[t + 128] + sq2[t + 192];
        if (s4 != 0.f) atomicAdd(&st[t], s4);
        if (q4 != 0.f) atomicAdd(&st[64 + t], q4);
    }
}

// ---------------- cleanup: stats for chunk-crossing nodes + empty nodes ----------------
__global__ __launch_bounds__(256) void cleanup_stats(
    const int* __restrict__ offs, const int* __restrict__ node_start,
    const float* __restrict__ AGG, float* __restrict__ stats, int n, int NC)
{
    const int t = threadIdx.x;
    const int lane = t & 63;
    const int wave = (blockIdx.x * 256 + t) >> 6;
    float lsum = 0.f, lsq = 0.f;

    if (wave < NC) {
        int c = wave;
        if (c > 0) {
            int nd = node_start[c];
            int s = offs[nd];
            if (s < c * CH && s >= (c - 1) * CH) {   // crosses boundary c, first crossing
                float y = fmaxf(AGG[((size_t)nd << 6) | lane], 0.f);
                lsum = y; lsq = y * y;
            }
        }
    } else {
        int base = (wave - NC) << 6;
        int nd = base + lane;
        bool empty = (nd < n) && (offs[nd + 1] == offs[nd]);
        unsigned long long mask = __ballot(empty);
        while (mask) {
            int b = __ffsll((unsigned long long)mask) - 1;
            mask &= mask - 1;
            int nd2 = base + b;
            float y = fmaxf(AGG[((size_t)nd2 << 6) | lane], 0.f);
            lsum += y; lsq = fmaf(y, y, lsq);
        }
    }

    __shared__ float ss[256], sq2[256];
    ss[t] = lsum; sq2[t] = lsq;
    __syncthreads();
    if (t < 64) {
        float* st = stats + ((blockIdx.x & (NREP - 1)) << 7);
        float s4 = ss[t] + ss[t + 64] + ss[t + 128] + ss[t + 192];
        float q4 = sq2[t] + sq2[t + 64] + sq2[t + 128] + sq2[t + 192];
        if (s4 != 0.f) atomicAdd(&st[t], s4);
        if (q4 != 0.f) atomicAdd(&st[64 + t], q4);
    }
}

// ---------------- apply (final layer): out = relu(AGG)*scale + shift, inline finalize ----------------
__global__ __launch_bounds__(256) void apply_bn(
    const float* __restrict__ AGG, const float* __restrict__ stats,
    const float* __restrict__ gamma, const float* __restrict__ beta,
    float* __restrict__ xout, int ntot4, int nrows)
{
    __shared__ float scsh[128];
    const int t = threadIdx.x;
    if (t < 64) {
        float s = 0.f, q = 0.f;
        #pragma unroll
        for (int rep = 0; rep < NREP; ++rep) {
            s += stats[rep * 128 + t];
            q += stats[rep * 128 + 64 + t];
        }
        float invN = 1.0f / (float)nrows;
        float mean = s * invN;
        float var  = q * invN - mean * mean;
        float sc   = gamma[t] * rsqrtf(var + BN_EPS);
        scsh[t] = sc;
        scsh[64 + t] = beta[t] - mean * sc;
    }
    __syncthreads();

    int idx = blockIdx.x * 256 + t;
    const int stride = gridDim.x * 256;
    for (; idx < ntot4; idx += stride) {
        float4 a = reinterpret_cast<const float4*>(AGG)[idx];
        int c4 = idx & 15;
        float4 sc = reinterpret_cast<const float4*>(scsh)[c4];
        float4 sh = reinterpret_cast<const float4*>(scsh)[16 + c4];
        float4 o;
        o.x = fmaxf(a.x, 0.f) * sc.x + sh.x;
        o.y = fmaxf(a.y, 0.f) * sc.y + sh.y;
        o.z = fmaxf(a.z, 0.f) * sc.z + sh.z;
        o.w = fmaxf(a.w, 0.f) * sc.w + sh.w;
        reinterpret_cast<float4*>(xout)[idx] = o;
    }
}

extern "C" void kernel_launch(void* const* d_in, const int* in_sizes, int n_in,
                              void* d_out, int out_size, void* d_ws, size_t ws_size,
                              hipStream_t stream)
{
    const float* x     = (const float*)d_in[0];
    const int*   ei    = (const int*)d_in[1];
    const float* Wk    = (const float*)d_in[3];
    const float* bk    = (const float*)d_in[4];
    const float* Wq    = (const float*)d_in[5];
    const float* bq    = (const float*)d_in[6];
    const float* Wv    = (const float*)d_in[7];
    const float* bv    = (const float*)d_in[8];
    const float* Ws    = (const float*)d_in[9];
    const float* bs    = (const float*)d_in[10];
    const float* bias  = (const float*)d_in[11];
    const float* gamma = (const float*)d_in[12];
    const float* beta  = (const float*)d_in[13];

    const int nrows  = in_sizes[0] / D;     // 100000
    const int nedges = in_sizes[1] / 2;     // 1250000
    const int nm     = nrows * D;
    const int NB     = (nrows + (1 << BSH) - 1) >> BSH;   // 782 buckets
    const int NC     = (nedges + CH - 1) / CH;            // chunks

    float* out = (float*)d_out;
    float* ws  = (float*)d_ws;
    unsigned short* EKh = (unsigned short*)ws;            // nm u16
    unsigned short* V16 = EKh + nm;                       // nm u16
    unsigned char*  EQ8 = (unsigned char*)(V16 + nm);     // nm u8
    float* AGG = (float*)(EQ8 + nm);                      // nm f32 (5*nm bytes offset: 16B-aligned)
    float* stats = AGG + nm;                              // 2*NREP*128 f32 (L1 | L2)
    int* offs    = (int*)(stats + 2 * NREP * 128);        // nrows+1
    unsigned int* bin = (unsigned int*)(offs + nrows + 1);// nedges
    int* csr_src = (int*)(bin + nedges);                  // nedges
    int* cnt     = csr_src + nedges;                      // NBLK*NB
    int* basel   = cnt + NBLK * NB;                       // NBLK*NB
    int* btot    = basel + NBLK * NB;                     // NB
    int* boff    = btot + NB;                             // NB
    int* nstart_map = boff + NB;                          // NC
    unsigned short* Wfrag = (unsigned short*)(nstart_map + NC);  // 32768 u16

    const int* srcI = ei;
    const int* dstI = ei + nedges;

    const int gemm_blocks = (nrows + 63) / 64;
    const int agg_blocks  = (NC + 3) / 4;                 // 1 wave per chunk
    const int clean_waves = NC + (nrows + 63) / 64;
    const int clean_blocks = (clean_waves + 3) / 4;

    float* statsL1 = stats;
    float* statsL2 = stats + NREP * 128;

    // ---- weight prep + matrix-binned CSR build ----
    prep_bin<<<128 + NBLK, 256, 0, stream>>>(Wk, Wq, Wv, Ws, Wfrag, dstI, cnt, nedges, NB);
    scan_mat<<<NB, 256, 0, stream>>>(cnt, basel, btot, NB);
    scan_buckets<<<1, 1024, 0, stream>>>(btot, boff, stats, offs, NB, nrows, nedges);
    bin_emit<<<NBLK, 256, 0, stream>>>(srcI, dstI, basel, boff, bin, nedges, NB);
    bucket_csr<<<NB, 256, 0, stream>>>(bin, boff, btot, offs, csr_src, nrows);
    nstart_bs<<<(NC + 255) / 256, 256, 0, stream>>>(offs, nstart_map, nrows, NC);

    // ---- layer 1 ----
    gemm_fused<false><<<gemm_blocks, 256, 0, stream>>>(x, Wfrag,
        bk, bq, bv, bs, bias, statsL1, gamma, beta, EKh, V16, EQ8, AGG, nrows);
    edge_agg<<<agg_blocks, 256, 0, stream>>>(csr_src, offs, nstart_map, EKh, V16, EQ8, AGG, statsL1, nrows);
    cleanup_stats<<<clean_blocks, 256, 0, stream>>>(offs, nstart_map, AGG, statsL1, nrows, NC);

    // ---- layer 2 (relu+BN of layer 1 computed inline from replicated raw sums) ----
    gemm_fused<true><<<gemm_blocks, 256, 0, stream>>>(AGG, Wfrag + 16384,
        bk + D, bq + D, bv + D, bs + D, bias + D, statsL1, gamma, beta, EKh, V16, EQ8, AGG, nrows);
    edge_agg<<<agg_blocks, 256, 0, stream>>>(csr_src, offs, nstart_map, EKh, V16, EQ8, AGG, statsL2, nrows);
    cleanup_stats<<<clean_blocks, 256, 0, stream>>>(offs, nstart_map, AGG, statsL2, nrows, NC);
    apply_bn<<<2048, 256, 0, stream>>>(AGG, statsL2, gamma + D, beta + D, out, nm / 4, nrows);
}

// Round 13
// 279.499 us; speedup vs baseline: 1.0562x; 1.0562x over previous
//
#include <hip/hip_runtime.h>
#include <math.h>

#define D 64
#define BN_EPS 1e-5f
#define CH 160          // edges per chunk (edge_agg work unit)
#define BSH 7           // bucket = 128 consecutive dst nodes
#define BCAP 8192       // per-bucket LDS capacity in bucket_csr (mean ~1600)
#define NBLK 256        // fat blocks for matrix binning
#define NREP 16         // stat-accumulator replicas (contention control)

using short8 = __attribute__((ext_vector_type(8))) short;
using f32x4  = __attribute__((ext_vector_type(4))) float;

static __device__ __forceinline__ unsigned short f2bf(float f) {
    unsigned int u = __float_as_uint(f);
    unsigned int r = (u + 0x7fffu + ((u >> 16) & 1u)) >> 16;
    return (unsigned short)r;
}
static __device__ __forceinline__ float bf2f(unsigned short u) {
    return __uint_as_float(((unsigned int)u) << 16);
}
static __device__ __forceinline__ float clamp60(float x) {
    return fminf(fmaxf(x, -60.f), 60.f);
}

// ---------------- merged: weight prep (blocks 0..127) + bucket histogram (blocks 128..383) ----------------
__global__ __launch_bounds__(256) void prep_bin(
    const float* __restrict__ Wk, const float* __restrict__ Wq,
    const float* __restrict__ Wv, const float* __restrict__ Ws,
    unsigned short* __restrict__ Wfrag,
    const int* __restrict__ dst, int* __restrict__ cnt, int nedges, int NB)
{
    const int t = threadIdx.x;
    if (blockIdx.x < 128) {
        int idx = blockIdx.x * 256 + t;      // 32768 total
        int i    = idx & 7;
        int lane = (idx >> 3) & 63;
        int kb   = (idx >> 9) & 1;
        int nc   = (idx >> 10) & 3;
        int m    = (idx >> 12) & 3;
        int l    = (idx >> 14) & 1;
        int k = kb * 32 + (lane >> 4) * 8 + i;
        int n = nc * 16 + (lane & 15);
        const float* W = (m == 0) ? Wk : (m == 1) ? Wq : (m == 2) ? Wv : Ws;
        Wfrag[idx] = f2bf(W[(size_t)l * 4096 + k * 64 + n]);
    } else {
        __shared__ int h[1024];
        const int b = blockIdx.x - 128;
        for (int i = t; i < NB; i += 256) h[i] = 0;
        __syncthreads();
        const int e0 = (int)(((long long)nedges * b) / NBLK);
        const int e1 = (int)(((long long)nedges * (b + 1)) / NBLK);
        for (int i = e0 + t; i < e1; i += 256)
            atomicAdd(&h[dst[i] >> BSH], 1);
        __syncthreads();
        for (int i = t; i < NB; i += 256) cnt[b * NB + i] = h[i];
    }
}

// ---------------- fused 4-GEMM via MFMA ----------------
// EKh = bf16(exp(-clamp k)); QV = {bf16(v)<<16 | bf16(exp(-clamp q))}; AGG = x@Ws+bs+bias.
template<bool APPLY_BN>
__global__ __launch_bounds__(256) void gemm_fused(
    const float* x,                       // may alias AGG (own rows only)
    const unsigned short* __restrict__ Wfrag,
    const float* __restrict__ bk, const float* __restrict__ bq,
    const float* __restrict__ bv, const float* __restrict__ bs,
    const float* __restrict__ bias, const float* __restrict__ stats,
    const float* __restrict__ gamma, const float* __restrict__ beta,
    unsigned short* __restrict__ EKh, unsigned int* __restrict__ QV,
    float* AGG, int nrows)
{
    __shared__ unsigned short xt[64 * 64];   // bf16 tile, XOR-swizzled 16B chunks
    __shared__ float scsh[128];              // [sc 0..63 | sh 64..127]
    const int t = threadIdx.x;
    const int row0 = blockIdx.x * 64;

    if (APPLY_BN) {
        if (t < 64) {
            float s = 0.f, q = 0.f;
            #pragma unroll
            for (int rep = 0; rep < NREP; ++rep) {
                s += stats[rep * 128 + t];
                q += stats[rep * 128 + 64 + t];
            }
            float invN = 1.0f / (float)nrows;
            float mean = s * invN;
            float var  = q * invN - mean * mean;
            float sc   = gamma[t] * rsqrtf(var + BN_EPS);
            scsh[t] = sc;
            scsh[64 + t] = beta[t] - mean * sc;
        }
        __syncthreads();
    }

    #pragma unroll
    for (int it = 0; it < 4; ++it) {
        int fidx = t + it * 256;
        int r = fidx >> 4, c4 = fidx & 15;
        int grow = row0 + r;
        float4 v = make_float4(0.f, 0.f, 0.f, 0.f);
        if (grow < nrows)
            v = *reinterpret_cast<const float4*>(&x[(size_t)grow * D + c4 * 4]);
        if (APPLY_BN) {
            float4 sc = reinterpret_cast<const float4*>(scsh)[c4];
            float4 sh = reinterpret_cast<const float4*>(scsh)[16 + c4];
            v.x = fmaxf(v.x, 0.f) * sc.x + sh.x;
            v.y = fmaxf(v.y, 0.f) * sc.y + sh.y;
            v.z = fmaxf(v.z, 0.f) * sc.z + sh.z;
            v.w = fmaxf(v.w, 0.f) * sc.w + sh.w;
        }
        ushort4 b;
        b.x = f2bf(v.x); b.y = f2bf(v.y); b.z = f2bf(v.z); b.w = f2bf(v.w);
        int phys = (c4 >> 1) ^ (r & 7);      // 16B-chunk XOR swizzle
        *reinterpret_cast<ushort4*>(&xt[r * 64 + phys * 8 + (c4 & 1) * 4]) = b;
    }
    __syncthreads();

    const int w = t >> 6, lane = t & 63;
    const int rbase = w * 16;

    short8 A[2];
    #pragma unroll
    for (int kb = 0; kb < 2; ++kb) {
        int r = rbase + (lane & 15);
        int c16 = (kb * 4 + (lane >> 4)) ^ (r & 7);
        A[kb] = *reinterpret_cast<const short8*>(&xt[r * 64 + c16 * 8]);
    }

    f32x4 acc[4][4];
    #pragma unroll
    for (int m = 0; m < 4; ++m)
        #pragma unroll
        for (int nc = 0; nc < 4; ++nc)
            acc[m][nc] = (f32x4){0.f, 0.f, 0.f, 0.f};

    #pragma unroll
    for (int nc = 0; nc < 4; ++nc) {
        #pragma unroll
        for (int m = 0; m < 4; ++m) {
            #pragma unroll
            for (int kb = 0; kb < 2; ++kb) {
                short8 B = *reinterpret_cast<const short8*>(
                    &Wfrag[((((m * 4 + nc) * 2 + kb) * 64) + lane) * 8]);
                acc[m][nc] = __builtin_amdgcn_mfma_f32_16x16x32_bf16(A[kb], B, acc[m][nc], 0, 0, 0);
            }
        }
    }

    const int crow = rbase + ((lane >> 4) << 2);
    #pragma unroll
    for (int nc = 0; nc < 4; ++nc) {
        int c = nc * 16 + (lane & 15);
        float bkc = bk[c], bqc = bq[c], bvc = bv[c], bsc = bs[c] + bias[c];
        #pragma unroll
        for (int reg = 0; reg < 4; ++reg) {
            int grow = row0 + crow + reg;
            if (grow < nrows) {
                size_t o = (size_t)grow * D + c;
                EKh[o] = f2bf(__expf(-clamp60(acc[0][nc][reg] + bkc)));
                float eq = __expf(-clamp60(acc[1][nc][reg] + bqc));
                QV[o] = ((unsigned int)f2bf(acc[2][nc][reg] + bvc) << 16) | (unsigned int)f2bf(eq);
                AGG[o] = acc[3][nc][reg] + bsc;
            }
        }
    }
}

// ---------------- matrix-binned CSR build (zero global atomics) ----------------
__global__ __launch_bounds__(256) void scan_mat(const int* __restrict__ cnt,
                                                int* __restrict__ basel,
                                                int* __restrict__ btot, int NB)
{
    __shared__ int tmp[256];
    const int k = blockIdx.x;    // bucket
    const int t = threadIdx.x;   // block index
    int v = cnt[t * NB + k];
    tmp[t] = v;
    __syncthreads();
    for (int off = 1; off < 256; off <<= 1) {
        int add = (t >= off) ? tmp[t - off] : 0;
        __syncthreads();
        tmp[t] += add;
        __syncthreads();
    }
    basel[t * NB + k] = tmp[t] - v;
    if (t == 255) btot[k] = tmp[255];
}

__global__ __launch_bounds__(1024) void scan_buckets(const int* __restrict__ btot,
                                                     int* __restrict__ boff,
                                                     float* __restrict__ stats,
                                                     int* __restrict__ offs,
                                                     int NB, int n, int nedges)
{
    __shared__ int tmp[1024];
    const int t = threadIdx.x;
    int v = (t < NB) ? btot[t] : 0;
    tmp[t] = v;
    __syncthreads();
    for (int off = 1; off < 1024; off <<= 1) {
        int add = (t >= off) ? tmp[t - off] : 0;
        __syncthreads();
        tmp[t] += add;
        __syncthreads();
    }
    if (t < NB) boff[t] = tmp[t] - v;
    for (int i = t; i < 2 * NREP * 128; i += 1024) stats[i] = 0.f;
    if (t == 0) offs[n] = nedges;
}

__global__ __launch_bounds__(256) void bin_emit(const int* __restrict__ src,
                                                const int* __restrict__ dst,
                                                const int* __restrict__ basel,
                                                const int* __restrict__ boff,
                                                unsigned int* __restrict__ bin,
                                                int nedges, int NB)
{
    __shared__ int cur[1024];
    const int t = threadIdx.x, b = blockIdx.x;
    for (int i = t; i < NB; i += 256) cur[i] = boff[i] + basel[b * NB + i];
    __syncthreads();
    const int e0 = (int)(((long long)nedges * b) / NBLK);
    const int e1 = (int)(((long long)nedges * (b + 1)) / NBLK);
    for (int i = e0 + t; i < e1; i += 256) {
        int d = dst[i];
        int pos = atomicAdd(&cur[d >> BSH], 1);
        bin[pos] = ((unsigned int)src[i] << BSH) | (unsigned int)(d & ((1 << BSH) - 1));
    }
}

__global__ __launch_bounds__(256) void bucket_csr(const unsigned int* __restrict__ bin,
                                                  const int* __restrict__ boff,
                                                  const int* __restrict__ btot,
                                                  int* __restrict__ offs,
                                                  int* __restrict__ csr_src, int n)
{
    __shared__ unsigned int lsrc[BCAP];
    __shared__ int ldeg[128], loff[128], lcur[128];
    const int t = threadIdx.x;
    const int b = blockIdx.x;
    const int base = boff[b];
    const int cnt  = btot[b];

    if (t < 128) ldeg[t] = 0;
    __syncthreads();
    for (int j = t; j < cnt; j += 256)
        atomicAdd(&ldeg[bin[base + j] & ((1 << BSH) - 1)], 1);
    __syncthreads();
    if (t < 128) loff[t] = ldeg[t];
    __syncthreads();
    for (int off = 1; off < 128; off <<= 1) {
        int add = (t < 128 && t >= off) ? loff[t - off] : 0;
        __syncthreads();
        if (t < 128) loff[t] += add;
        __syncthreads();
    }
    if (t < 128) {
        int ex = loff[t] - ldeg[t];
        lcur[t] = ex;
        int node = (b << BSH) + t;
        if (node < n) offs[node] = base + ex;
    }
    __syncthreads();
    for (int j = t; j < cnt; j += 256) {
        unsigned int e = bin[base + j];
        int pos = atomicAdd(&lcur[e & ((1 << BSH) - 1)], 1);
        lsrc[pos] = e >> BSH;
    }
    __syncthreads();
    for (int j = t; j < cnt; j += 256)
        csr_src[base + j] = (int)lsrc[j];
}

__global__ __launch_bounds__(256) void nstart_bs(const int* __restrict__ offs,
                                                 int* __restrict__ node_start,
                                                 int n, int NC)
{
    int c = blockIdx.x * 256 + threadIdx.x;
    if (c >= NC) return;
    int target = c * CH;
    int a = 0, bnd = n;
    while (a < bnd) {
        int mid = (a + bnd) >> 1;
        if (offs[mid + 1] > target) bnd = mid; else a = mid + 1;
    }
    node_start[c] = a;
}

// ---------------- edge-parallel aggregation + fused BN stats (replicated accumulators) ----------------
__global__ __launch_bounds__(256) void edge_agg(
    const int* __restrict__ csr_src, const int* __restrict__ offs,
    const int* __restrict__ node_start,
    const unsigned short* __restrict__ EKh, const unsigned int* __restrict__ QV,
    float* __restrict__ AGG, float* __restrict__ stats, int nnodes)
{
    const int t = threadIdx.x;
    const int lane  = t & 63;
    const int chunk = __builtin_amdgcn_readfirstlane((int)((blockIdx.x * 256 + t) >> 6));
    const int Etot  = offs[nnodes];
    const int e0 = chunk * CH;
    float lsum = 0.f, lsq = 0.f;

    if (e0 < Etot) {
        const int e1 = min(e0 + CH, Etot);

        int n      = node_start[chunk];
        int nstart = offs[n];
        int nend   = offs[n + 1];

        float acc = 0.f;
        float ek  = bf2f(EKh[((size_t)n << 6) | lane]);

        auto flush = [&](bool partial) {
            int idx = (n << 6) | lane;
            if (partial) {
                atomicAdd(&AGG[idx], acc);
            } else {
                float cur = AGG[idx] + acc;      // final value: all edges owned here
                AGG[idx] = cur;
                float y = fmaxf(cur, 0.f);
                lsum += y;
                lsq = fmaf(y, y, lsq);
            }
        };
        auto advance = [&](int eidx) {
            do { ++n; } while (offs[n + 1] == eidx);   // skip empty nodes
            nstart = eidx;
            nend   = offs[n + 1];
            acc = 0.f;
            ek  = bf2f(EKh[((size_t)n << 6) | lane]);
        };

        for (int e = e0; e < e1; e += 64) {
            const int cnt = min(64, e1 - e);
            int sAll = (lane < cnt) ? csr_src[e + lane] : 0;
            for (int b = 0; b < cnt; b += 16) {
                const int bc = min(16, cnt - b);
                unsigned int p[16];
                #pragma unroll
                for (int u = 0; u < 16; ++u) {
                    if (u < bc) {
                        int s = __shfl(sAll, b + u);
                        p[u] = QV[((size_t)s << 6) | lane];
                    }
                }
                #pragma unroll
                for (int u = 0; u < 16; ++u) {
                    if (u < bc) {
                        int eidx = e + b + u;
                        if (eidx == nend) { flush(nstart < e0); advance(eidx); }
                        float eq = __uint_as_float(p[u] << 16);
                        float vv = __uint_as_float(p[u] & 0xffff0000u);
                        float g  = __builtin_amdgcn_rcpf(fmaf(ek, eq, 1.0f));
                        acc = fmaf(g, vv, acc);
                    }
                }
            }
        }
        flush((nstart < e0) || (nend > e1));
    }

    __shared__ float ss[256], sq2[256];
    ss[t] = lsum; sq2[t] = lsq;
    __syncthreads();
    if (t < 64) {
        float* st = stats + ((blockIdx.x & (NREP - 1)) << 7);
        float s4 = ss[t] + ss[t + 64] + ss[t + 128] + ss[t + 192];
        float q4 = sq2[t] + sq2[t + 64] + sq2[t + 128] + sq2[t + 192];
        if (s4 != 0.f) atomicAdd(&st[t], s4);
        if (q4 != 0.f) atomicAdd(&st[64 + t], q4);
    }
}

// ---------------- cleanup: stats for chunk-crossing nodes + empty nodes ----------------
__global__ __launch_bounds__(256) void cleanup_stats(
    const int* __restrict__ offs, const int* __restrict__ node_start,
    const float* __restrict__ AGG, float* __restrict__ stats, int n, int NC)
{
    const int t = threadIdx.x;
    const int lane = t & 63;
    const int wave = (blockIdx.x * 256 + t) >> 6;
    float lsum = 0.f, lsq = 0.f;

    if (wave < NC) {
        int c = wave;
        if (c > 0) {
            int nd = node_start[c];
            int s = offs[nd];
            if (s < c * CH && s >= (c - 1) * CH) {   // crosses boundary c, first crossing
                float y = fmaxf(AGG[((size_t)nd << 6) | lane], 0.f);
                lsum = y; lsq = y * y;
            }
        }
    } else {
        int base = (wave - NC) << 6;
        int nd = base + lane;
        bool empty = (nd < n) && (offs[nd + 1] == offs[nd]);
        unsigned long long mask = __ballot(empty);
        while (mask) {
            int b = __ffsll((unsigned long long)mask) - 1;
            mask &= mask - 1;
            int nd2 = base + b;
            float y = fmaxf(AGG[((size_t)nd2 << 6) | lane], 0.f);
            lsum += y; lsq = fmaf(y, y, lsq);
        }
    }

    __shared__ float ss[256], sq2[256];
    ss[t] = lsum; sq2[t] = lsq;
    __syncthreads();
    if (t < 64) {
        float* st = stats + ((blockIdx.x & (NREP - 1)) << 7);
        float s4 = ss[t] + ss[t + 64] + ss[t + 128] + ss[t + 192];
        float q4 = sq2[t] + sq2[t + 64] + sq2[t + 128] + sq2[t + 192];
        if (s4 != 0.f) atomicAdd(&st[t], s4);
        if (q4 != 0.f) atomicAdd(&st[64 + t], q4);
    }
}

// ---------------- apply (final layer): out = relu(AGG)*scale + shift, inline finalize ----------------
__global__ __launch_bounds__(256) void apply_bn(
    const float* __restrict__ AGG, const float* __restrict__ stats,
    const float* __restrict__ gamma, const float* __restrict__ beta,
    float* __restrict__ xout, int ntot4, int nrows)
{
    __shared__ float scsh[128];
    const int t = threadIdx.x;
    if (t < 64) {
        float s = 0.f, q = 0.f;
        #pragma unroll
        for (int rep = 0; rep < NREP; ++rep) {
            s += stats[rep * 128 + t];
            q += stats[rep * 128 + 64 + t];
        }
        float invN = 1.0f / (float)nrows;
        float mean = s * invN;
        float var  = q * invN - mean * mean;
        float sc   = gamma[t] * rsqrtf(var + BN_EPS);
        scsh[t] = sc;
        scsh[64 + t] = beta[t] - mean * sc;
    }
    __syncthreads();

    int idx = blockIdx.x * 256 + t;
    const int stride = gridDim.x * 256;
    for (; idx < ntot4; idx += stride) {
        float4 a = reinterpret_cast<const float4*>(AGG)[idx];
        int c4 = idx & 15;
        float4 sc = reinterpret_cast<const float4*>(scsh)[c4];
        float4 sh = reinterpret_cast<const float4*>(scsh)[16 + c4];
        float4 o;
        o.x = fmaxf(a.x, 0.f) * sc.x + sh.x;
        o.y = fmaxf(a.y, 0.f) * sc.y + sh.y;
        o.z = fmaxf(a.z, 0.f) * sc.z + sh.z;
        o.w = fmaxf(a.w, 0.f) * sc.w + sh.w;
        reinterpret_cast<float4*>(xout)[idx] = o;
    }
}

extern "C" void kernel_launch(void* const* d_in, const int* in_sizes, int n_in,
                              void* d_out, int out_size, void* d_ws, size_t ws_size,
                              hipStream_t stream)
{
    const float* x     = (const float*)d_in[0];
    const int*   ei    = (const int*)d_in[1];
    const float* Wk    = (const float*)d_in[3];
    const float* bk    = (const float*)d_in[4];
    const float* Wq    = (const float*)d_in[5];
    const float* bq    = (const float*)d_in[6];
    const float* Wv    = (const float*)d_in[7];
    const float* bv    = (const float*)d_in[8];
    const float* Ws    = (const float*)d_in[9];
    const float* bs    = (const float*)d_in[10];
    const float* bias  = (const float*)d_in[11];
    const float* gamma = (const float*)d_in[12];
    const float* beta  = (const float*)d_in[13];

    const int nrows  = in_sizes[0] / D;     // 100000
    const int nedges = in_sizes[1] / 2;     // 1250000
    const int nm     = nrows * D;
    const int NB     = (nrows + (1 << BSH) - 1) >> BSH;   // 782 buckets
    const int NC     = (nedges + CH - 1) / CH;            // chunks

    float* out = (float*)d_out;
    float* ws  = (float*)d_ws;
    unsigned short* EKh = (unsigned short*)ws;            // nm u16
    unsigned int* QV = (unsigned int*)(EKh + nm);         // nm u32
    float* AGG = (float*)(QV + nm);                       // nm f32
    float* stats = AGG + nm;                              // 2*NREP*128 f32 (L1 | L2)
    int* offs    = (int*)(stats + 2 * NREP * 128);        // nrows+1
    unsigned int* bin = (unsigned int*)(offs + nrows + 1);// nedges
    int* csr_src = (int*)(bin + nedges);                  // nedges
    int* cnt     = csr_src + nedges;                      // NBLK*NB
    int* basel   = cnt + NBLK * NB;                       // NBLK*NB
    int* btot    = basel + NBLK * NB;                     // NB
    int* boff    = btot + NB;                             // NB
    int* nstart_map = boff + NB;                          // NC
    unsigned short* Wfrag = (unsigned short*)(nstart_map + NC);  // 32768 u16

    const int* srcI = ei;
    const int* dstI = ei + nedges;

    const int gemm_blocks = (nrows + 63) / 64;
    const int agg_blocks  = (NC + 3) / 4;                 // 1 wave per chunk
    const int clean_waves = NC + (nrows + 63) / 64;
    const int clean_blocks = (clean_waves + 3) / 4;

    float* statsL1 = stats;
    float* statsL2 = stats + NREP * 128;

    // ---- weight prep + matrix-binned CSR build ----
    prep_bin<<<128 + NBLK, 256, 0, stream>>>(Wk, Wq, Wv, Ws, Wfrag, dstI, cnt, nedges, NB);
    scan_mat<<<NB, 256, 0, stream>>>(cnt, basel, btot, NB);
    scan_buckets<<<1, 1024, 0, stream>>>(btot, boff, stats, offs, NB, nrows, nedges);
    bin_emit<<<NBLK, 256, 0, stream>>>(srcI, dstI, basel, boff, bin, nedges, NB);
    bucket_csr<<<NB, 256, 0, stream>>>(bin, boff, btot, offs, csr_src, nrows);
    nstart_bs<<<(NC + 255) / 256, 256, 0, stream>>>(offs, nstart_map, nrows, NC);

    // ---- layer 1 ----
    gemm_fused<false><<<gemm_blocks, 256, 0, stream>>>(x, Wfrag,
        bk, bq, bv, bs, bias, statsL1, gamma, beta, EKh, QV, AGG, nrows);
    edge_agg<<<agg_blocks, 256, 0, stream>>>(csr_src, offs, nstart_map, EKh, QV, AGG, statsL1, nrows);
    cleanup_stats<<<clean_blocks, 256, 0, stream>>>(offs, nstart_map, AGG, statsL1, nrows, NC);

    // ---- layer 2 (relu+BN of layer 1 computed inline from replicated raw sums) ----
    gemm_fused<true><<<gemm_blocks, 256, 0, stream>>>(AGG, Wfrag + 16384,
        bk + D, bq + D, bv + D, bs + D, bias + D, statsL1, gamma, beta, EKh, QV, AGG, nrows);
    edge_agg<<<agg_blocks, 256, 0, stream>>>(csr_src, offs, nstart_map, EKh, QV, AGG, statsL2, nrows);
    cleanup_stats<<<clean_blocks, 256, 0, stream>>>(offs, nstart_map, AGG, statsL2, nrows, NC);
    apply_bn<<<2048, 256, 0, stream>>>(AGG, statsL2, gamma + D, beta + D, out, nm / 4, nrows);
}